// Round 2
// baseline (441.500 us; speedup 1.0000x reference)
//
#include <hip/hip_runtime.h>

#define BATCH 8192
#define DIM   2048   // IN_DIM == OUT_DIM
#define DEPTH 5

#define TM 128
#define TN 128
#define BK 32
#define KDIM 2048

typedef short bf16x8_t __attribute__((ext_vector_type(8)));
typedef float f32x4_t  __attribute__((ext_vector_type(4)));

// ---- bf16 split helpers (RNE, bit-manip) ----
__device__ __forceinline__ unsigned short f2bf(float f) {
  unsigned u = __float_as_uint(f);
  u += 0x7fffu + ((u >> 16) & 1u);
  return (unsigned short)(u >> 16);
}
__device__ __forceinline__ float bf2f(unsigned short h) {
  return __uint_as_float(((unsigned)h) << 16);
}

// ============================================================================
// Fused prep (one dispatch):
//  blocks [0, 16384)        : split x (8192x2048 f32 -> bf16 hi/lo)
//  blocks [16384, 20480)    : W (KxN f32) -> W^T hi/lo (NxK bf16), LDS transpose
//  blocks [20480, 20488)    : bias2[j] = b[j] + (1/2048)*prod_d cos(hdw[d,j,0])^2
//    (scan preserves uniformity along axis1 -> rolls cancel; phases vanish)
// ============================================================================
__global__ void prep_fused_kernel(const float* __restrict__ x,
                                  const float* __restrict__ hdw,
                                  const float* __restrict__ W,
                                  const float* __restrict__ bias,
                                  float* __restrict__ bias2,
                                  ushort4* __restrict__ xhi4,
                                  ushort4* __restrict__ xlo4,
                                  unsigned short* __restrict__ whi,
                                  unsigned short* __restrict__ wlo) {
  __shared__ float tile[32][33];
  const int b = blockIdx.x;
  const int tid = threadIdx.x;

  if (b < 16384) {  // ---- split x ----
    size_t i = (size_t)b * 256 + tid;
    float4 v = ((const float4*)x)[i];
    ushort4 h, l;
    h.x = f2bf(v.x); l.x = f2bf(v.x - bf2f(h.x));
    h.y = f2bf(v.y); l.y = f2bf(v.y - bf2f(h.y));
    h.z = f2bf(v.z); l.z = f2bf(v.z - bf2f(h.z));
    h.w = f2bf(v.w); l.w = f2bf(v.w - bf2f(h.w));
    xhi4[i] = h;
    xlo4[i] = l;
  } else if (b < 20480) {  // ---- transpose+split W ----
    const int t = b - 16384;
    const int tx = tid & 31;   // 0..31
    const int ty = tid >> 5;   // 0..7
    const int n0 = (t & 63) * 32;
    const int k0 = (t >> 6) * 32;
#pragma unroll
    for (int r = 0; r < 32; r += 8)
      tile[ty + r][tx] = W[(size_t)(k0 + ty + r) * DIM + n0 + tx];
    __syncthreads();
#pragma unroll
    for (int r = 0; r < 32; r += 8) {
      float v = tile[tx][ty + r];                 // = W[k0+tx][n0+ty+r]
      unsigned short h = f2bf(v);
      unsigned short l = f2bf(v - bf2f(h));
      size_t o = (size_t)(n0 + ty + r) * DIM + k0 + tx;  // wT[n][k]
      whi[o] = h;
      wlo[o] = l;
    }
  } else {  // ---- bias2 ----
    int j = (b - 20480) * 256 + tid;
    float p = 1.0f;
#pragma unroll
    for (int d = 0; d < DEPTH; ++d)
      p *= cosf(hdw[(size_t)d * DIM * DIM + (size_t)j * DIM]);
    bias2[j] = bias[j] + p * p * (1.0f / 2048.0f);
  }
}

// ============================================================================
// GEMM: C = A@W via bf16x3 MFMA; out = tanh(C + bias2)
// 128x128 tile, BK=32, 4 waves (2x2), wave = 64x64 = 4x4 of 16x16x32 MFMA.
//
// LDS tile layout is PERMUTED for conflict-free reads: chunk (8 bf16 = 16 B)
// index s = row_group*64 + kc*16 + row_in16, so a frag read for row block rg
// lands at byte offset rg*1024 + lane*16 — linear in lane (2-way wrap only,
// which is free). slot->LDS is the fixed global_load_lds mapping; we permute
// the slot->GLOBAL side instead (still 16x 64-B segments per instruction).
// ============================================================================
__device__ __forceinline__ void stage_tile(const unsigned short* gbase,
                                           unsigned short* s, int wave, int lane) {
#pragma unroll
  for (int r = 0; r < 2; ++r) {
    const int rg = r * 4 + wave;  // row group 0..7 (16 rows each)
    const unsigned short* gp =
        gbase + (size_t)(rg * 16 + (lane & 15)) * KDIM + (lane >> 4) * 8;
    unsigned short* lp = s + (r * 256 + wave * 64) * 8;  // wave-uniform base
    __builtin_amdgcn_global_load_lds(
        (const __attribute__((address_space(1))) void*)gp,
        (__attribute__((address_space(3))) void*)lp, 16, 0, 0);
  }
}

__global__ __launch_bounds__(256) void gemm_x3_kernel(
    const unsigned short* __restrict__ Ahi, const unsigned short* __restrict__ Alo,
    const unsigned short* __restrict__ Bhi, const unsigned short* __restrict__ Blo,
    const float* __restrict__ bias2, float* __restrict__ out) {
  __shared__ __attribute__((aligned(16))) unsigned short sAhi[TM * BK];
  __shared__ __attribute__((aligned(16))) unsigned short sAlo[TM * BK];
  __shared__ __attribute__((aligned(16))) unsigned short sBhi[TN * BK];
  __shared__ __attribute__((aligned(16))) unsigned short sBlo[TN * BK];

  const int tid  = threadIdx.x;
  const int wave = tid >> 6;
  const int lane = tid & 63;
  const int bm = blockIdx.x;   // consecutive bm share bn -> W strip stays L2-hot
  const int bn = blockIdx.y;
  const int wm = wave >> 1, wn = wave & 1;
  const int l15 = lane & 15, kl = lane >> 4;

  const unsigned short* agh = Ahi + (size_t)bm * TM * KDIM;
  const unsigned short* agl = Alo + (size_t)bm * TM * KDIM;
  const unsigned short* bgh = Bhi + (size_t)bn * TN * KDIM;
  const unsigned short* bgl = Blo + (size_t)bn * TN * KDIM;

  // frag read offsets: row block rg = wm*4+i (A) / wn*4+i (B), linear in lane
  int aidx[4], bidx[4];
#pragma unroll
  for (int i = 0; i < 4; ++i) {
    aidx[i] = (wm * 4 + i) * 512 + lane * 8;
    bidx[i] = (wn * 4 + i) * 512 + lane * 8;
  }

  const f32x4_t vzero = {0.f, 0.f, 0.f, 0.f};
  f32x4_t acc[4][4];
#pragma unroll
  for (int i = 0; i < 4; ++i)
#pragma unroll
    for (int j = 0; j < 4; ++j) acc[i][j] = vzero;

  for (int kt = 0; kt < KDIM / BK; ++kt) {
    if (kt) __syncthreads();  // all waves done reading previous LDS tiles
    const int ko = kt * BK;
    stage_tile(agh + ko, sAhi, wave, lane);
    stage_tile(agl + ko, sAlo, wave, lane);
    stage_tile(bgh + ko, sBhi, wave, lane);
    stage_tile(bgl + ko, sBlo, wave, lane);
    asm volatile("s_waitcnt vmcnt(0)" ::: "memory");
    __syncthreads();

    bf16x8_t ah[4], al[4], bh[4], bl[4];
#pragma unroll
    for (int i = 0; i < 4; ++i) {
      ah[i] = *(const bf16x8_t*)(sAhi + aidx[i]);
      al[i] = *(const bf16x8_t*)(sAlo + aidx[i]);
      bh[i] = *(const bf16x8_t*)(sBhi + bidx[i]);
      bl[i] = *(const bf16x8_t*)(sBlo + bidx[i]);
    }
#pragma unroll
    for (int i = 0; i < 4; ++i)
#pragma unroll
      for (int j = 0; j < 4; ++j) {
        acc[i][j] = __builtin_amdgcn_mfma_f32_16x16x32_bf16(ah[i], bh[j], acc[i][j], 0, 0, 0);
        acc[i][j] = __builtin_amdgcn_mfma_f32_16x16x32_bf16(ah[i], bl[j], acc[i][j], 0, 0, 0);
        acc[i][j] = __builtin_amdgcn_mfma_f32_16x16x32_bf16(al[i], bh[j], acc[i][j], 0, 0, 0);
      }
  }

  // Epilogue: C/D layout col = lane&15, row = (lane>>4)*4 + reg  [m89/m91]
  const int orow0 = bm * TM + wm * 64;
  const int ocol0 = bn * TN + wn * 64;
#pragma unroll
  for (int j = 0; j < 4; ++j) {
    const int col = ocol0 + j * 16 + l15;
    const float b2 = bias2[col];
#pragma unroll
    for (int i = 0; i < 4; ++i) {
      const int row = orow0 + i * 16 + kl * 4;
#pragma unroll
      for (int r = 0; r < 4; ++r) {
        float z = acc[i][j][r] + b2;
        // tanh(z) = 1 - 2/(exp(2z)+1)
        float e = __expf(2.0f * z);
        out[(size_t)(row + r) * DIM + col] = 1.0f - 2.0f / (e + 1.0f);
      }
    }
  }
}

// ============================================================================
extern "C" void kernel_launch(void* const* d_in, const int* in_sizes, int n_in,
                              void* d_out, int out_size, void* d_ws, size_t ws_size,
                              hipStream_t stream) {
  const float* x   = (const float*)d_in[0];
  const float* hdw = (const float*)d_in[1];
  const float* W   = (const float*)d_in[2];
  const float* b   = (const float*)d_in[3];
  float* out = (float*)d_out;

  // workspace layout (~80.01 MB)
  char* ws = (char*)d_ws;
  float*          bias2 = (float*)ws;                               // 8 KB
  unsigned short* xhi   = (unsigned short*)(ws + 8192);             // 32 MB
  unsigned short* xlo   = xhi + (size_t)BATCH * DIM;                // 32 MB
  unsigned short* wThi  = xlo + (size_t)BATCH * DIM;                // 8 MB
  unsigned short* wTlo  = wThi + (size_t)DIM * DIM;                 // 8 MB

  prep_fused_kernel<<<20488, 256, 0, stream>>>(
      x, hdw, W, b, bias2, (ushort4*)xhi, (ushort4*)xlo, wThi, wTlo);
  gemm_x3_kernel<<<dim3(BATCH / TM, DIM / TN), 256, 0, stream>>>(
      xhi, xlo, wThi, wTlo, bias2, out);
}

// Round 3
// 393.045 us; speedup vs baseline: 1.1233x; 1.1233x over previous
//
#include <hip/hip_runtime.h>

#define BATCH 8192
#define DIM   2048   // IN_DIM == OUT_DIM
#define DEPTH 5

#define TM 128
#define TN 128
#define BK 32
#define KDIM 2048

typedef short bf16x8_t __attribute__((ext_vector_type(8)));
typedef float f32x4_t  __attribute__((ext_vector_type(4)));

// ---- bf16 split helpers (RNE, bit-manip) ----
__device__ __forceinline__ unsigned short f2bf(float f) {
  unsigned u = __float_as_uint(f);
  u += 0x7fffu + ((u >> 16) & 1u);
  return (unsigned short)(u >> 16);
}
__device__ __forceinline__ float bf2f(unsigned short h) {
  return __uint_as_float(((unsigned)h) << 16);
}

// ============================================================================
// Fused prep (one dispatch):
//  blocks [0, 16384)        : split x (8192x2048 f32 -> bf16 hi/lo)
//  blocks [16384, 20480)    : W (KxN f32) -> W^T hi/lo (NxK bf16), LDS transpose
//  blocks [20480, 20488)    : bias2[j] = b[j] + (1/2048)*prod_d cos(hdw[d,j,0])^2
//    (scan preserves uniformity along axis1 -> rolls cancel; phases vanish)
// ============================================================================
__global__ void prep_fused_kernel(const float* __restrict__ x,
                                  const float* __restrict__ hdw,
                                  const float* __restrict__ W,
                                  const float* __restrict__ bias,
                                  float* __restrict__ bias2,
                                  ushort4* __restrict__ xhi4,
                                  ushort4* __restrict__ xlo4,
                                  unsigned short* __restrict__ whi,
                                  unsigned short* __restrict__ wlo) {
  __shared__ float tile[32][33];
  const int b = blockIdx.x;
  const int tid = threadIdx.x;

  if (b < 16384) {  // ---- split x ----
    size_t i = (size_t)b * 256 + tid;
    float4 v = ((const float4*)x)[i];
    ushort4 h, l;
    h.x = f2bf(v.x); l.x = f2bf(v.x - bf2f(h.x));
    h.y = f2bf(v.y); l.y = f2bf(v.y - bf2f(h.y));
    h.z = f2bf(v.z); l.z = f2bf(v.z - bf2f(h.z));
    h.w = f2bf(v.w); l.w = f2bf(v.w - bf2f(h.w));
    xhi4[i] = h;
    xlo4[i] = l;
  } else if (b < 20480) {  // ---- transpose+split W ----
    const int t = b - 16384;
    const int tx = tid & 31;   // 0..31
    const int ty = tid >> 5;   // 0..7
    const int n0 = (t & 63) * 32;
    const int k0 = (t >> 6) * 32;
#pragma unroll
    for (int r = 0; r < 32; r += 8)
      tile[ty + r][tx] = W[(size_t)(k0 + ty + r) * DIM + n0 + tx];
    __syncthreads();
#pragma unroll
    for (int r = 0; r < 32; r += 8) {
      float v = tile[tx][ty + r];                 // = W[k0+tx][n0+ty+r]
      unsigned short h = f2bf(v);
      unsigned short l = f2bf(v - bf2f(h));
      size_t o = (size_t)(n0 + ty + r) * DIM + k0 + tx;  // wT[n][k]
      whi[o] = h;
      wlo[o] = l;
    }
  } else {  // ---- bias2 ----
    int j = (b - 20480) * 256 + tid;
    float p = 1.0f;
#pragma unroll
    for (int d = 0; d < DEPTH; ++d)
      p *= cosf(hdw[(size_t)d * DIM * DIM + (size_t)j * DIM]);
    bias2[j] = bias[j] + p * p * (1.0f / 2048.0f);
  }
}

// ============================================================================
// GEMM: C = A@W via bf16x3 MFMA; out = tanh(C + bias2)
// 128x128 tile, BK=32, 4 waves (2x2), wave = 64x64 = 4x4 of 16x16x32 MFMA.
//
// LDS layout: chunk (16 B = 8 bf16) at position p = row*4 + (kc ^ ((row>>1)&3)).
// Staging (global_load_lds, LDS side fixed = base + lane*16): each aligned
// 4-lane quad reads the 4 chunks of ONE row's 64-B line (internally XOR-
// permuted -> same line, quad-merge intact). Frag reads: aligned 8-lane
// groups hit 8 distinct 16-B bank quads -> conflict-free ds_read_b128.
// ============================================================================
__device__ __forceinline__ void stage_tile(const unsigned short* gbase,
                                           unsigned short* s, int wave, int lane) {
#pragma unroll
  for (int r = 0; r < 2; ++r) {
    const int p = r * 256 + wave * 64 + lane;   // chunk position in LDS
    const int row = p >> 2;
    const int kc = (p & 3) ^ ((row >> 1) & 3);
    const unsigned short* gp = gbase + (size_t)row * KDIM + kc * 8;
    unsigned short* lp = s + (size_t)(r * 256 + wave * 64) * 8;  // wave-uniform
    __builtin_amdgcn_global_load_lds(
        (const __attribute__((address_space(1))) void*)gp,
        (__attribute__((address_space(3))) void*)lp, 16, 0, 0);
  }
}

__global__ __launch_bounds__(256) void gemm_x3_kernel(
    const unsigned short* __restrict__ Ahi, const unsigned short* __restrict__ Alo,
    const unsigned short* __restrict__ Bhi, const unsigned short* __restrict__ Blo,
    const float* __restrict__ bias2, float* __restrict__ out) {
  __shared__ __attribute__((aligned(16))) unsigned short sAhi[TM * BK];
  __shared__ __attribute__((aligned(16))) unsigned short sAlo[TM * BK];
  __shared__ __attribute__((aligned(16))) unsigned short sBhi[TN * BK];
  __shared__ __attribute__((aligned(16))) unsigned short sBlo[TN * BK];

  const int tid  = threadIdx.x;
  const int wave = tid >> 6;
  const int lane = tid & 63;
  const int bm = blockIdx.x;   // consecutive bm share bn -> W strip stays L2-hot
  const int bn = blockIdx.y;
  const int wm = wave >> 1, wn = wave & 1;
  const int l15 = lane & 15, kl = lane >> 4;

  const unsigned short* agh = Ahi + (size_t)bm * TM * KDIM;
  const unsigned short* agl = Alo + (size_t)bm * TM * KDIM;
  const unsigned short* bgh = Bhi + (size_t)bn * TN * KDIM;
  const unsigned short* bgl = Blo + (size_t)bn * TN * KDIM;

  // frag read offsets (ushort units): row*32 + swizzled_chunk*8
  const int swz = (kl ^ ((l15 >> 1) & 3)) * 8;
  int aidx[4], bidx[4];
#pragma unroll
  for (int i = 0; i < 4; ++i) {
    aidx[i] = ((wm * 4 + i) * 16 + l15) * 32 + swz;
    bidx[i] = ((wn * 4 + i) * 16 + l15) * 32 + swz;
  }

  const f32x4_t vzero = {0.f, 0.f, 0.f, 0.f};
  f32x4_t acc[4][4];
#pragma unroll
  for (int i = 0; i < 4; ++i)
#pragma unroll
    for (int j = 0; j < 4; ++j) acc[i][j] = vzero;

  for (int kt = 0; kt < KDIM / BK; ++kt) {
    if (kt) __syncthreads();  // all waves done reading previous LDS tiles
    const int ko = kt * BK;
    stage_tile(agh + ko, sAhi, wave, lane);
    stage_tile(agl + ko, sAlo, wave, lane);
    stage_tile(bgh + ko, sBhi, wave, lane);
    stage_tile(bgl + ko, sBlo, wave, lane);
    asm volatile("s_waitcnt vmcnt(0)" ::: "memory");
    __syncthreads();

    bf16x8_t ah[4], al[4], bh[4], bl[4];
#pragma unroll
    for (int i = 0; i < 4; ++i) {
      ah[i] = *(const bf16x8_t*)(sAhi + aidx[i]);
      al[i] = *(const bf16x8_t*)(sAlo + aidx[i]);
      bh[i] = *(const bf16x8_t*)(sBhi + bidx[i]);
      bl[i] = *(const bf16x8_t*)(sBlo + bidx[i]);
    }
#pragma unroll
    for (int i = 0; i < 4; ++i)
#pragma unroll
      for (int j = 0; j < 4; ++j) {
        acc[i][j] = __builtin_amdgcn_mfma_f32_16x16x32_bf16(ah[i], bh[j], acc[i][j], 0, 0, 0);
        acc[i][j] = __builtin_amdgcn_mfma_f32_16x16x32_bf16(ah[i], bl[j], acc[i][j], 0, 0, 0);
        acc[i][j] = __builtin_amdgcn_mfma_f32_16x16x32_bf16(al[i], bh[j], acc[i][j], 0, 0, 0);
      }
  }

  // Epilogue: C/D layout col = lane&15, row = (lane>>4)*4 + reg  [m89/m91]
  const int orow0 = bm * TM + wm * 64;
  const int ocol0 = bn * TN + wn * 64;
#pragma unroll
  for (int j = 0; j < 4; ++j) {
    const int col = ocol0 + j * 16 + l15;
    const float b2 = bias2[col];
#pragma unroll
    for (int i = 0; i < 4; ++i) {
      const int row = orow0 + i * 16 + kl * 4;
#pragma unroll
      for (int r = 0; r < 4; ++r) {
        float z = acc[i][j][r] + b2;
        // tanh(z) = 1 - 2/(exp(2z)+1)
        float e = __expf(2.0f * z);
        out[(size_t)(row + r) * DIM + col] = 1.0f - 2.0f / (e + 1.0f);
      }
    }
  }
}

// ============================================================================
extern "C" void kernel_launch(void* const* d_in, const int* in_sizes, int n_in,
                              void* d_out, int out_size, void* d_ws, size_t ws_size,
                              hipStream_t stream) {
  const float* x   = (const float*)d_in[0];
  const float* hdw = (const float*)d_in[1];
  const float* W   = (const float*)d_in[2];
  const float* b   = (const float*)d_in[3];
  float* out = (float*)d_out;

  // workspace layout (~80.01 MB)
  char* ws = (char*)d_ws;
  float*          bias2 = (float*)ws;                               // 8 KB
  unsigned short* xhi   = (unsigned short*)(ws + 8192);             // 32 MB
  unsigned short* xlo   = xhi + (size_t)BATCH * DIM;                // 32 MB
  unsigned short* wThi  = xlo + (size_t)BATCH * DIM;                // 8 MB
  unsigned short* wTlo  = wThi + (size_t)DIM * DIM;                 // 8 MB

  prep_fused_kernel<<<20488, 256, 0, stream>>>(
      x, hdw, W, b, bias2, (ushort4*)xhi, (ushort4*)xlo, wThi, wTlo);
  gemm_x3_kernel<<<dim3(BATCH / TM, DIM / TN), 256, 0, stream>>>(
      xhi, xlo, wThi, wTlo, bias2, out);
}

// Round 5
// 358.947 us; speedup vs baseline: 1.2300x; 1.0950x over previous
//
#include <hip/hip_runtime.h>

#define BATCH 8192
#define DIM   2048   // IN_DIM == OUT_DIM
#define DEPTH 5
#define KDIM  2048

// Fragment-ready operand layout: operand (M x K) stored as chunks of 8 bf16.
// chunk(tile, kt, l) = X[m = tile*16 + (l&15)][k = kt*32 + (l>>4)*8 .. +8]
// flat index = ((tile*64 + kt)*64 + l) * 8 ushorts.  A lane's MFMA fragment
// load is then base + lane*16 B : perfectly coalesced global_load_dwordx4,
// no LDS round-trip, no barriers in the GEMM K-loop.
#define TILE_STRIDE 32768  // 64 kt * 64 l * 8 ushorts

typedef short bf16x8_t __attribute__((ext_vector_type(8)));
typedef float f32x4_t  __attribute__((ext_vector_type(4)));

// ---- bf16 split helpers (RNE, bit-manip) ----
__device__ __forceinline__ unsigned short f2bf(float f) {
  unsigned u = __float_as_uint(f);
  u += 0x7fffu + ((u >> 16) & 1u);
  return (unsigned short)(u >> 16);
}
__device__ __forceinline__ float bf2f(unsigned short h) {
  return __uint_as_float(((unsigned)h) << 16);
}

// ============================================================================
// Fused prep (one dispatch):
//  blocks [0, 8192)      : split x -> frag-ready xhi/xlo chunks
//  blocks [8192, 12288)  : W (KxN) -> transpose+split -> frag-ready whi/wlo
//  blocks [12288, 12296) : bias2[j] = b[j] + (1/2048)*prod_d cos(hdw[d,j,0])^2
//    (scan preserves uniformity along axis1 -> rolls cancel; phases vanish)
// ============================================================================
__global__ void prep_fused_kernel(const float* __restrict__ x,
                                  const float* __restrict__ hdw,
                                  const float* __restrict__ W,
                                  const float* __restrict__ bias,
                                  float* __restrict__ bias2,
                                  unsigned short* __restrict__ xhi,
                                  unsigned short* __restrict__ xlo,
                                  unsigned short* __restrict__ whi,
                                  unsigned short* __restrict__ wlo) {
  __shared__ float tile[32][33];
  const int b = blockIdx.x;
  const int tid = threadIdx.x;

  if (b < 8192) {  // ---- split x into frag-ready chunks ----
    size_t g = (size_t)b * 256 + tid;       // chunk id, 0..2097151
    const int l = (int)(g & 63);
    const size_t grp = g >> 6;              // tile*64 + kt
    const size_t m = (grp >> 6) * 16 + (l & 15);
    const size_t k = (grp & 63) * 32 + (size_t)(l >> 4) * 8;
    const float4* xp = (const float4*)(x + m * KDIM + k);
    float4 v0 = xp[0], v1 = xp[1];
    float v[8] = {v0.x, v0.y, v0.z, v0.w, v1.x, v1.y, v1.z, v1.w};
    bf16x8_t h, lo;
#pragma unroll
    for (int j = 0; j < 8; ++j) {
      unsigned short hj = f2bf(v[j]);
      h[j] = (short)hj;
      lo[j] = (short)f2bf(v[j] - bf2f(hj));
    }
    ((bf16x8_t*)xhi)[g] = h;
    ((bf16x8_t*)xlo)[g] = lo;
  } else if (b < 12288) {  // ---- transpose+split W into frag-ready chunks ----
    const int t = b - 8192;
    const int tx = tid & 31;   // 0..31
    const int ty = tid >> 5;   // 0..7
    const int n0 = (t & 63) * 32;
    const int k0 = (t >> 6) * 32;
#pragma unroll
    for (int r = 0; r < 32; r += 8)
      tile[ty + r][tx] = W[(size_t)(k0 + ty + r) * DIM + n0 + tx];
    __syncthreads();
    // 128 chunks (2 n-subtiles x 64 lanes); threads 0-127 write hi, 128-255 lo
    const int c = tid & 127, half = tid >> 7;
    const int sub = c >> 6, l = c & 63;
    const int nn = sub * 16 + (l & 15);
    const int kc = l >> 4;
    bf16x8_t outv;
#pragma unroll
    for (int j = 0; j < 8; ++j) {
      float vv = tile[kc * 8 + j][nn];       // = W[k0+kc*8+j][n0+nn]
      unsigned short hj = f2bf(vv);
      outv[j] = half ? (short)f2bf(vv - bf2f(hj)) : (short)hj;
    }
    const size_t tile_n = (size_t)(t & 63) * 2 + sub;
    const size_t o = (tile_n * 64 + (t >> 6)) * 64 + l;  // chunk id
    ((bf16x8_t*)(half ? wlo : whi))[o] = outv;
  } else {  // ---- bias2 ----
    int j = (b - 12288) * 256 + tid;
    float p = 1.0f;
#pragma unroll
    for (int d = 0; d < DEPTH; ++d)
      p *= cosf(hdw[(size_t)d * DIM * DIM + (size_t)j * DIM]);
    bias2[j] = bias[j] + p * p * (1.0f / 2048.0f);
  }
}

// ============================================================================
// Barrier-free GEMM: C = A@W via bf16x3 MFMA; out = tanh(C + bias2).
// 128x128 block tile, 4 waves (2x2), wave = 64x64 = 4x4 of 16x16x32 MFMA.
// Operands are in frag-ready layout: each wave loads its 16 fragments per
// K-iter straight from global (L1/L2-served), register double-buffered.
// NO LDS, NO __syncthreads in the K-loop -> compiler emits partial vmcnt
// waits (AITER-style pipelining the 2-barrier structure couldn't express).
// NOTE: last iteration prefetches one kt past the strip; ws layout places
// bias2 after wTlo so these reads stay inside the workspace.
// ============================================================================
__global__ __launch_bounds__(256, 2) void gemm_direct_kernel(
    const unsigned short* __restrict__ Ah, const unsigned short* __restrict__ Al,
    const unsigned short* __restrict__ Bh, const unsigned short* __restrict__ Bl,
    const float* __restrict__ bias2, float* __restrict__ out) {
  const int tid  = threadIdx.x;
  const int wave = tid >> 6;
  const int lane = tid & 63;
  const int bm = blockIdx.x;   // consecutive bm share bn -> B strip L2/L1-hot
  const int bn = blockIdx.y;
  const int wm = wave >> 1, wn = wave & 1;
  const int l15 = lane & 15, kl = lane >> 4;

  const int tm0 = bm * 8 + wm * 4;  // m-tile (16 rows) base
  const int tn0 = bn * 8 + wn * 4;

  const unsigned short* pAh[4]; const unsigned short* pAl[4];
  const unsigned short* pBh[4]; const unsigned short* pBl[4];
#pragma unroll
  for (int i = 0; i < 4; ++i) {
    pAh[i] = Ah + (size_t)(tm0 + i) * TILE_STRIDE;
    pAl[i] = Al + (size_t)(tm0 + i) * TILE_STRIDE;
    pBh[i] = Bh + (size_t)(tn0 + i) * TILE_STRIDE;
    pBl[i] = Bl + (size_t)(tn0 + i) * TILE_STRIDE;
  }
  int voff = lane * 8;  // ushort offset within strip; +512 per kt

  const f32x4_t vzero = {0.f, 0.f, 0.f, 0.f};
  f32x4_t acc[4][4];
#pragma unroll
  for (int i = 0; i < 4; ++i)
#pragma unroll
    for (int j = 0; j < 4; ++j) acc[i][j] = vzero;

  bf16x8_t ah[4], al[4], bh[4], bl[4];
#pragma unroll
  for (int i = 0; i < 4; ++i) {
    ah[i] = *(const bf16x8_t*)(pAh[i] + voff);
    al[i] = *(const bf16x8_t*)(pAl[i] + voff);
    bh[i] = *(const bf16x8_t*)(pBh[i] + voff);
    bl[i] = *(const bf16x8_t*)(pBl[i] + voff);
  }

#pragma unroll 2
  for (int kt = 0; kt < KDIM / 32; ++kt) {
    // prefetch kt+1 (register double-buffer; OOB-safe, see note above)
    const int nv = voff + 512;
    bf16x8_t nah[4], nal[4], nbh[4], nbl[4];
#pragma unroll
    for (int i = 0; i < 4; ++i) {
      nah[i] = *(const bf16x8_t*)(pAh[i] + nv);
      nal[i] = *(const bf16x8_t*)(pAl[i] + nv);
      nbh[i] = *(const bf16x8_t*)(pBh[i] + nv);
      nbl[i] = *(const bf16x8_t*)(pBl[i] + nv);
    }
#pragma unroll
    for (int i = 0; i < 4; ++i)
#pragma unroll
      for (int j = 0; j < 4; ++j) {
        acc[i][j] = __builtin_amdgcn_mfma_f32_16x16x32_bf16(ah[i], bh[j], acc[i][j], 0, 0, 0);
        acc[i][j] = __builtin_amdgcn_mfma_f32_16x16x32_bf16(ah[i], bl[j], acc[i][j], 0, 0, 0);
        acc[i][j] = __builtin_amdgcn_mfma_f32_16x16x32_bf16(al[i], bh[j], acc[i][j], 0, 0, 0);
      }
#pragma unroll
    for (int i = 0; i < 4; ++i) {
      ah[i] = nah[i]; al[i] = nal[i]; bh[i] = nbh[i]; bl[i] = nbl[i];
    }
    voff = nv;
  }

  // Epilogue: C/D layout col = lane&15, row = (lane>>4)*4 + reg  [m89/m91]
  const int orow0 = bm * 128 + wm * 64;
  const int ocol0 = bn * 128 + wn * 64;
#pragma unroll
  for (int j = 0; j < 4; ++j) {
    const int col = ocol0 + j * 16 + l15;
    const float b2 = bias2[col];
#pragma unroll
    for (int i = 0; i < 4; ++i) {
      const int row = orow0 + i * 16 + kl * 4;
#pragma unroll
      for (int r = 0; r < 4; ++r) {
        float z = acc[i][j][r] + b2;
        // tanh(z) = 1 - 2/(exp(2z)+1)
        float e = __expf(2.0f * z);
        out[(size_t)(row + r) * DIM + col] = 1.0f - 2.0f / (e + 1.0f);
      }
    }
  }
}

// ============================================================================
extern "C" void kernel_launch(void* const* d_in, const int* in_sizes, int n_in,
                              void* d_out, int out_size, void* d_ws, size_t ws_size,
                              hipStream_t stream) {
  const float* x   = (const float*)d_in[0];
  const float* hdw = (const float*)d_in[1];
  const float* W   = (const float*)d_in[2];
  const float* b   = (const float*)d_in[3];
  float* out = (float*)d_out;

  // workspace layout (~80.01 MB); bias2 LAST so tail prefetch stays in ws
  char* ws = (char*)d_ws;
  unsigned short* xhi  = (unsigned short*)ws;                       // 32 MB
  unsigned short* xlo  = xhi + (size_t)BATCH * DIM;                 // 32 MB
  unsigned short* wThi = xlo + (size_t)BATCH * DIM;                 // 8 MB
  unsigned short* wTlo = wThi + (size_t)DIM * DIM;                  // 8 MB
  float*          bias2 = (float*)(wTlo + (size_t)DIM * DIM);       // 8 KB

  prep_fused_kernel<<<12296, 256, 0, stream>>>(
      x, hdw, W, b, bias2, xhi, xlo, wThi, wTlo);
  gemm_direct_kernel<<<dim3(BATCH / 128, DIM / 128), 256, 0, stream>>>(
      xhi, xlo, wThi, wTlo, bias2, out);
}